// Round 2
// baseline (247.541 us; speedup 1.0000x reference)
//
#include <hip/hip_runtime.h>
#include <stdint.h>

// GCN: out = relu(adj @ (x @ W) + b)
// x:[32,1024,128] f32, adj:[32,1024,1024] f32, W:[128,128] f32, b:[128] f32
// v3: LDS-free streaming MFMA for k1 and k2.
//   Insight: adj (and x) have ZERO reuse across waves -> LDS staging was pure
//   overhead (load+cvt+ds_write+barrier+ds_read for single-use data). The only
//   shared operands (WT 32KB, ST 8MB) are L2/L3-resident, so per-fragment
//   global reads are cache hits. Fragment geometry is cache-line perfect:
//   A-frag = 32 contiguous B/lane (f32), rows covered as full 128B lines;
//   B-frag = 16 contiguous B/lane (bf16). No barriers -> vmcnt never drained,
//   compiler keeps ~16 loads in flight per wave.
// MFMA order identical to v2 -> bit-identical output.

typedef short bf16x8 __attribute__((ext_vector_type(8)));       // 8 bf16 (4 VGPRs)
typedef float f32x4 __attribute__((ext_vector_type(4)));
typedef unsigned short u16x8 __attribute__((ext_vector_type(8)));

__device__ __forceinline__ unsigned short f2bf(float f) {
    uint32_t u = __builtin_bit_cast(uint32_t, f);
    u += 0x7FFFu + ((u >> 16) & 1u);   // RTNE
    return (unsigned short)(u >> 16);
}

__device__ __forceinline__ bf16x8 cvt8(f32x4 v0, f32x4 v1) {
    u16x8 p;
    p[0] = f2bf(v0.x); p[1] = f2bf(v0.y); p[2] = f2bf(v0.z); p[3] = f2bf(v0.w);
    p[4] = f2bf(v1.x); p[5] = f2bf(v1.y); p[6] = f2bf(v1.z); p[7] = f2bf(v1.w);
    return __builtin_bit_cast(bf16x8, p);
}

// ---------------- k0: WT[h][f] = bf16(W[f][h]) ----------------
__global__ __launch_bounds__(256) void k0_wt(const float* __restrict__ W,
                                             unsigned short* __restrict__ WT) {
    int o = blockIdx.x * 256 + threadIdx.x;  // flat over [h][f]
    int h = o >> 7, f = o & 127;
    WT[o] = f2bf(W[f * 128 + h]);
}

// ---------------- k1: ST[b][h][m] = sum_f WT[h][f] * x[b][m][f] ----------------
// D'[h][m] per block: 128 h x 64 m, K=128. LDS-free: A-frags direct from WT
// (bf16, L2-hot), B-frags direct from x rows (f32 -> cvt in reg).
__global__ __launch_bounds__(256) void k1_support(const float* __restrict__ x,
                                                  const unsigned short* __restrict__ WT,
                                                  unsigned short* __restrict__ ST) {
    int t = threadIdx.x;
    int wv = t >> 6, lane = t & 63, l16 = lane & 15, quad = lane >> 4;
    int wave_h = (wv & 1) * 64, wave_m = (wv >> 1) * 32;
    int node_base = blockIdx.x * 64;
    const float* xb = x + (size_t)node_base * 128;

    f32x4 acc[4][2];
#pragma unroll
    for (int ht = 0; ht < 4; ++ht)
#pragma unroll
        for (int mt = 0; mt < 2; ++mt) acc[ht][mt] = 0.f;

#pragma unroll
    for (int s = 0; s < 4; ++s) {
        int ko = s * 32 + quad * 8;
        bf16x8 a[4], bb[2];
#pragma unroll
        for (int ht = 0; ht < 4; ++ht)
            a[ht] = *(const bf16x8*)&WT[(wave_h + ht * 16 + l16) * 128 + ko];
#pragma unroll
        for (int mt = 0; mt < 2; ++mt) {
            const float* xr = xb + (size_t)(wave_m + mt * 16 + l16) * 128 + ko;
            bb[mt] = cvt8(*(const f32x4*)xr, *(const f32x4*)(xr + 4));
        }
#pragma unroll
        for (int ht = 0; ht < 4; ++ht)
#pragma unroll
            for (int mt = 0; mt < 2; ++mt)
                acc[ht][mt] = __builtin_amdgcn_mfma_f32_16x16x32_bf16(
                    a[ht], bb[mt], acc[ht][mt], 0, 0, 0);
    }

    int batch = blockIdx.x >> 4;
    int m_in_b = (blockIdx.x & 15) * 64;
#pragma unroll
    for (int ht = 0; ht < 4; ++ht)
#pragma unroll
        for (int mt = 0; mt < 2; ++mt) {
            int mcol = wave_m + mt * 16 + l16;
#pragma unroll
            for (int r = 0; r < 4; ++r) {
                int h = wave_h + ht * 16 + quad * 4 + r;
                ST[(((size_t)batch * 128 + h) << 10) + m_in_b + mcol] =
                    f2bf(acc[ht][mt][r]);
            }
        }
}

// ---------------- k2: out[b][m][n] = relu(sum_k adj[b][m][k]*S[b][k][n] + bias[n]) ----
// Per block: 64 m x 128 n, 4 waves -> 32m x 64n each. LDS-free: A-frags
// (adj rows, f32 -> cvt) and B-frags (ST rows, bf16) direct from global.
// No barriers: loads pipeline freely across K-steps.
__global__ __launch_bounds__(256) void k2_gcn(const float* __restrict__ adj,
                                              const unsigned short* __restrict__ ST,
                                              const float* __restrict__ bias,
                                              float* __restrict__ out) {
    int t = threadIdx.x;
    int batch = blockIdx.x >> 4;
    int mbase = (blockIdx.x & 15) * 64;
    int wv = t >> 6, lane = t & 63, l16 = lane & 15, quad = lane >> 4;
    int wave_m = (wv & 1) * 32, wave_n = (wv >> 1) * 64;

    float bv[4];
#pragma unroll
    for (int j = 0; j < 4; ++j) bv[j] = bias[wave_n + j * 16 + l16];

    f32x4 acc[2][4];
#pragma unroll
    for (int i = 0; i < 2; ++i)
#pragma unroll
        for (int j = 0; j < 4; ++j) acc[i][j] = 0.f;

    const float* adjb = adj + ((size_t)batch * 1024 + mbase) * 1024;
    const unsigned short* stb = ST + ((size_t)batch * 128) * 1024;

    for (int kb = 0; kb < 16; ++kb) {
#pragma unroll
        for (int s = 0; s < 2; ++s) {
            int ko = kb * 64 + s * 32 + quad * 8;
            bf16x8 a[2], bb[4];
#pragma unroll
            for (int i = 0; i < 2; ++i) {
                const float* ar = adjb + (size_t)(wave_m + i * 16 + l16) * 1024 + ko;
                a[i] = cvt8(*(const f32x4*)ar, *(const f32x4*)(ar + 4));
            }
#pragma unroll
            for (int j = 0; j < 4; ++j)
                bb[j] = *(const bf16x8*)&stb[(size_t)(wave_n + j * 16 + l16) * 1024 + ko];
#pragma unroll
            for (int i = 0; i < 2; ++i)
#pragma unroll
                for (int j = 0; j < 4; ++j)
                    acc[i][j] = __builtin_amdgcn_mfma_f32_16x16x32_bf16(
                        a[i], bb[j], acc[i][j], 0, 0, 0);
        }
    }

    float* outb = out + ((size_t)batch * 1024 + mbase) * 128;
#pragma unroll
    for (int i = 0; i < 2; ++i)
#pragma unroll
        for (int j = 0; j < 4; ++j) {
            int n = wave_n + j * 16 + l16;
#pragma unroll
            for (int r = 0; r < 4; ++r) {
                int m = wave_m + i * 16 + quad * 4 + r;
                float v = acc[i][j][r] + bv[j];
                outb[(size_t)m * 128 + n] = fmaxf(v, 0.f);
            }
        }
}

extern "C" void kernel_launch(void* const* d_in, const int* in_sizes, int n_in,
                              void* d_out, int out_size, void* d_ws, size_t ws_size,
                              hipStream_t stream) {
    const float* x = (const float*)d_in[0];
    const float* adj = (const float*)d_in[1];
    const float* W = (const float*)d_in[2];
    const float* b = (const float*)d_in[3];
    float* out = (float*)d_out;

    // ws layout: ST bf16 [32][128][1024] = 8 MiB, then WT bf16 [128][128] = 32 KiB
    unsigned short* ST = (unsigned short*)d_ws;
    unsigned short* WT = (unsigned short*)d_ws + (size_t)32 * 128 * 1024;

    k0_wt<<<64, 256, 0, stream>>>(W, WT);
    k1_support<<<512, 256, 0, stream>>>(x, WT, ST);
    k2_gcn<<<512, 256, 0, stream>>>(adj, ST, b, out);
}

// Round 3
// 230.020 us; speedup vs baseline: 1.0762x; 1.0762x over previous
//
#include <hip/hip_runtime.h>
#include <stdint.h>

// GCN: out = relu(adj @ (x @ W) + b)
// x:[32,1024,128] f32, adj:[32,1024,1024] f32, W:[128,128] f32, b:[128] f32
// v4: k2 occupancy fix. v3 showed k2 at 1.35 TB/s, 20% occupancy, VGPR=56
//   (zero pipelining regs) -> latency-bound. v2's LDS k2 was better but its
//   54 KB LDS + grid 512 capped it at 2 blocks/CU (8 waves/CU).
//   New k2: 32m x 128n tile, single-buffer LDS (23 KB), grid 1024
//   -> 4 blocks/CU = 16 waves/CU. Cooperative wide-load staging (proven
//   pattern) + simple stage/sync/MFMA/sync loop. Math order identical.
// k1 stays LDS-free streaming (v3; attribution says it improved ~6 us).

typedef short bf16x8 __attribute__((ext_vector_type(8)));       // 8 bf16 (4 VGPRs)
typedef float f32x4 __attribute__((ext_vector_type(4)));
typedef int i32x4 __attribute__((ext_vector_type(4)));
typedef unsigned short u16x4 __attribute__((ext_vector_type(4)));
typedef unsigned short u16x8 __attribute__((ext_vector_type(8)));

__device__ __forceinline__ unsigned short f2bf(float f) {
    uint32_t u = __builtin_bit_cast(uint32_t, f);
    u += 0x7FFFu + ((u >> 16) & 1u);   // RTNE
    return (unsigned short)(u >> 16);
}

__device__ __forceinline__ bf16x8 cvt8(f32x4 v0, f32x4 v1) {
    u16x8 p;
    p[0] = f2bf(v0.x); p[1] = f2bf(v0.y); p[2] = f2bf(v0.z); p[3] = f2bf(v0.w);
    p[4] = f2bf(v1.x); p[5] = f2bf(v1.y); p[6] = f2bf(v1.z); p[7] = f2bf(v1.w);
    return __builtin_bit_cast(bf16x8, p);
}

// ---------------- k0: WT[h][f] = bf16(W[f][h]) ----------------
__global__ __launch_bounds__(256) void k0_wt(const float* __restrict__ W,
                                             unsigned short* __restrict__ WT) {
    int o = blockIdx.x * 256 + threadIdx.x;  // flat over [h][f]
    int h = o >> 7, f = o & 127;
    WT[o] = f2bf(W[f * 128 + h]);
}

// ---------------- k1: ST[b][h][m] = sum_f WT[h][f] * x[b][m][f] ----------------
// D'[h][m] per block: 128 h x 64 m, K=128. LDS-free: A-frags direct from WT
// (bf16, L2-hot), B-frags direct from x rows (f32 -> cvt in reg).
__global__ __launch_bounds__(256) void k1_support(const float* __restrict__ x,
                                                  const unsigned short* __restrict__ WT,
                                                  unsigned short* __restrict__ ST) {
    int t = threadIdx.x;
    int wv = t >> 6, lane = t & 63, l16 = lane & 15, quad = lane >> 4;
    int wave_h = (wv & 1) * 64, wave_m = (wv >> 1) * 32;
    int node_base = blockIdx.x * 64;
    const float* xb = x + (size_t)node_base * 128;

    f32x4 acc[4][2];
#pragma unroll
    for (int ht = 0; ht < 4; ++ht)
#pragma unroll
        for (int mt = 0; mt < 2; ++mt) acc[ht][mt] = 0.f;

#pragma unroll
    for (int s = 0; s < 4; ++s) {
        int ko = s * 32 + quad * 8;
        bf16x8 a[4], bb[2];
#pragma unroll
        for (int ht = 0; ht < 4; ++ht)
            a[ht] = *(const bf16x8*)&WT[(wave_h + ht * 16 + l16) * 128 + ko];
#pragma unroll
        for (int mt = 0; mt < 2; ++mt) {
            const float* xr = xb + (size_t)(wave_m + mt * 16 + l16) * 128 + ko;
            bb[mt] = cvt8(*(const f32x4*)xr, *(const f32x4*)(xr + 4));
        }
#pragma unroll
        for (int ht = 0; ht < 4; ++ht)
#pragma unroll
            for (int mt = 0; mt < 2; ++mt)
                acc[ht][mt] = __builtin_amdgcn_mfma_f32_16x16x32_bf16(
                    a[ht], bb[mt], acc[ht][mt], 0, 0, 0);
    }

    int batch = blockIdx.x >> 4;
    int m_in_b = (blockIdx.x & 15) * 64;
#pragma unroll
    for (int ht = 0; ht < 4; ++ht)
#pragma unroll
        for (int mt = 0; mt < 2; ++mt) {
            int mcol = wave_m + mt * 16 + l16;
#pragma unroll
            for (int r = 0; r < 4; ++r) {
                int h = wave_h + ht * 16 + quad * 4 + r;
                ST[(((size_t)batch * 128 + h) << 10) + m_in_b + mcol] =
                    f2bf(acc[ht][mt][r]);
            }
        }
}

// ---------------- k2: out[b][m][n] = relu(sum_k adj[b][m][k]*S[b][k][n] + bias[n]) ----
// v4: 32m x 128n per block, grid 1024, 4 waves (each 32m x 32n), K in BK=64.
// LDS: As 32x72 + Bs 128x72 bf16 = 23 KB -> 4 blocks/CU (grid-limited),
// 16 waves/CU. Cooperative staging: 2 f32x4 (adj) + 4 dwordx4 (ST) per thread.
#define K2S 72  // LDS row stride (bf16): 144B = 9*16B -> uniform b128 bank slots
__global__ __launch_bounds__(256) void k2_gcn(const float* __restrict__ adj,
                                              const unsigned short* __restrict__ ST,
                                              const float* __restrict__ bias,
                                              float* __restrict__ out) {
    __shared__ __align__(16) unsigned short As[32 * K2S];   // adj tile [m][k] bf16
    __shared__ __align__(16) unsigned short Bs[128 * K2S];  // ST tile [n][k] bf16
    int t = threadIdx.x;
    int batch = blockIdx.x >> 5;
    int mbase = (blockIdx.x & 31) * 32;
    int wv = t >> 6, lane = t & 63, l16 = lane & 15, quad = lane >> 4;
    int wave_n = wv * 32;

    float bv[2];
#pragma unroll
    for (int j = 0; j < 2; ++j) bv[j] = bias[wave_n + j * 16 + l16];

    f32x4 acc[2][2];
#pragma unroll
    for (int i = 0; i < 2; ++i)
#pragma unroll
        for (int j = 0; j < 2; ++j) acc[i][j] = 0.f;

    const float* adjb = adj + ((size_t)batch * 1024 + mbase) * 1024;
    const unsigned short* stb = ST + ((size_t)batch * 128) * 1024;

    for (int kb = 0; kb < 16; ++kb) {
        // stage adj 32x64 fp32 -> bf16 LDS (2 f32x4 per thread)
#pragma unroll
        for (int i = 0; i < 2; ++i) {
            int c = i * 256 + t;
            int row = c >> 4, c4 = c & 15;
            f32x4 v = *(const f32x4*)(adjb + (size_t)row * 1024 + kb * 64 + c4 * 4);
            u16x4 p;
            p.x = f2bf(v.x); p.y = f2bf(v.y); p.z = f2bf(v.z); p.w = f2bf(v.w);
            *(u16x4*)&As[row * K2S + c4 * 4] = p;
        }
        // stage ST 128(n) x 64(k) bf16 (4 dwordx4 per thread)
#pragma unroll
        for (int i = 0; i < 4; ++i) {
            int c = i * 256 + t;
            int row = c >> 3, ch = c & 7;
            *(i32x4*)&Bs[row * K2S + ch * 8] =
                *(const i32x4*)(stb + (size_t)row * 1024 + kb * 64 + ch * 8);
        }
        __syncthreads();
#pragma unroll
        for (int s = 0; s < 2; ++s) {
            int ko = s * 32 + quad * 8;
            bf16x8 a[2], bb[2];
#pragma unroll
            for (int i = 0; i < 2; ++i)
                a[i] = *(const bf16x8*)&As[(i * 16 + l16) * K2S + ko];
#pragma unroll
            for (int j = 0; j < 2; ++j)
                bb[j] = *(const bf16x8*)&Bs[(wave_n + j * 16 + l16) * K2S + ko];
#pragma unroll
            for (int i = 0; i < 2; ++i)
#pragma unroll
                for (int j = 0; j < 2; ++j)
                    acc[i][j] = __builtin_amdgcn_mfma_f32_16x16x32_bf16(
                        a[i], bb[j], acc[i][j], 0, 0, 0);
        }
        __syncthreads();
    }

    float* outb = out + ((size_t)batch * 1024 + mbase) * 128;
#pragma unroll
    for (int i = 0; i < 2; ++i)
#pragma unroll
        for (int j = 0; j < 2; ++j) {
            int n = wave_n + j * 16 + l16;
#pragma unroll
            for (int r = 0; r < 4; ++r) {
                int m = i * 16 + quad * 4 + r;
                float v = acc[i][j][r] + bv[j];
                outb[(size_t)m * 128 + n] = fmaxf(v, 0.f);
            }
        }
}

extern "C" void kernel_launch(void* const* d_in, const int* in_sizes, int n_in,
                              void* d_out, int out_size, void* d_ws, size_t ws_size,
                              hipStream_t stream) {
    const float* x = (const float*)d_in[0];
    const float* adj = (const float*)d_in[1];
    const float* W = (const float*)d_in[2];
    const float* b = (const float*)d_in[3];
    float* out = (float*)d_out;

    // ws layout: ST bf16 [32][128][1024] = 8 MiB, then WT bf16 [128][128] = 32 KiB
    unsigned short* ST = (unsigned short*)d_ws;
    unsigned short* WT = (unsigned short*)d_ws + (size_t)32 * 128 * 1024;

    k0_wt<<<64, 256, 0, stream>>>(W, WT);
    k1_support<<<512, 256, 0, stream>>>(x, WT, ST);
    k2_gcn<<<1024, 256, 0, stream>>>(adj, ST, b, out);
}

// Round 4
// 228.237 us; speedup vs baseline: 1.0846x; 1.0078x over previous
//
#include <hip/hip_runtime.h>
#include <stdint.h>

// GCN: out = relu(adj @ (x @ W) + b)
// x:[32,1024,128] f32, adj:[32,1024,1024] f32, W:[128,128] f32, b:[128] f32
// v5: k2 = v2 geometry (64m x 128n, grid 512, dbuf LDS) + T4 counted-vmcnt
//   pipeline: reg-staged loads issued 2 K-steps ahead; raw s_barrier with
//   lgkmcnt(0)-only fence so global loads stay in flight ACROSS barriers
//   (never vmcnt(0) in the main loop -- the documented m97-stall fix).
//   Ledger: k2_stream=86.9us, k2_v4(4blk/CU)=69us, k2_v2(2-barrier)=59us;
//   all ~2.5-3.5x above the ~24us HBM floor -> stall is the per-iter drain.
// k1 stays LDS-free streaming (~3us). MFMA order identical -> bit-identical.

typedef short bf16x8 __attribute__((ext_vector_type(8)));       // 8 bf16 (4 VGPRs)
typedef float f32x4 __attribute__((ext_vector_type(4)));
typedef int i32x4 __attribute__((ext_vector_type(4)));
typedef unsigned short u16x4 __attribute__((ext_vector_type(4)));
typedef unsigned short u16x8 __attribute__((ext_vector_type(8)));

__device__ __forceinline__ unsigned short f2bf(float f) {
    uint32_t u = __builtin_bit_cast(uint32_t, f);
    u += 0x7FFFu + ((u >> 16) & 1u);   // RTNE
    return (unsigned short)(u >> 16);
}

__device__ __forceinline__ bf16x8 cvt8(f32x4 v0, f32x4 v1) {
    u16x8 p;
    p[0] = f2bf(v0.x); p[1] = f2bf(v0.y); p[2] = f2bf(v0.z); p[3] = f2bf(v0.w);
    p[4] = f2bf(v1.x); p[5] = f2bf(v1.y); p[6] = f2bf(v1.z); p[7] = f2bf(v1.w);
    return __builtin_bit_cast(bf16x8, p);
}

// LDS-visibility-only barrier: waits DS ops, NOT outstanding global loads.
// Memory-clobber asm on both sides pins all memory ops on their side of the
// s_barrier; global loads issued earlier remain in flight (counted vmcnt).
#define BAR_LGKM()                                                \
    do {                                                          \
        asm volatile("s_waitcnt lgkmcnt(0)" ::: "memory");        \
        __builtin_amdgcn_s_barrier();                             \
        asm volatile("" ::: "memory");                            \
    } while (0)

// ---------------- k0: WT[h][f] = bf16(W[f][h]) ----------------
__global__ __launch_bounds__(256) void k0_wt(const float* __restrict__ W,
                                             unsigned short* __restrict__ WT) {
    int o = blockIdx.x * 256 + threadIdx.x;  // flat over [h][f]
    int h = o >> 7, f = o & 127;
    WT[o] = f2bf(W[f * 128 + h]);
}

// ---------------- k1: ST[b][h][m] = sum_f WT[h][f] * x[b][m][f] ----------------
// D'[h][m] per block: 128 h x 64 m, K=128. LDS-free: A-frags direct from WT
// (bf16, L2-hot), B-frags direct from x rows (f32 -> cvt in reg).
__global__ __launch_bounds__(256) void k1_support(const float* __restrict__ x,
                                                  const unsigned short* __restrict__ WT,
                                                  unsigned short* __restrict__ ST) {
    int t = threadIdx.x;
    int wv = t >> 6, lane = t & 63, l16 = lane & 15, quad = lane >> 4;
    int wave_h = (wv & 1) * 64, wave_m = (wv >> 1) * 32;
    int node_base = blockIdx.x * 64;
    const float* xb = x + (size_t)node_base * 128;

    f32x4 acc[4][2];
#pragma unroll
    for (int ht = 0; ht < 4; ++ht)
#pragma unroll
        for (int mt = 0; mt < 2; ++mt) acc[ht][mt] = 0.f;

#pragma unroll
    for (int s = 0; s < 4; ++s) {
        int ko = s * 32 + quad * 8;
        bf16x8 a[4], bb[2];
#pragma unroll
        for (int ht = 0; ht < 4; ++ht)
            a[ht] = *(const bf16x8*)&WT[(wave_h + ht * 16 + l16) * 128 + ko];
#pragma unroll
        for (int mt = 0; mt < 2; ++mt) {
            const float* xr = xb + (size_t)(wave_m + mt * 16 + l16) * 128 + ko;
            bb[mt] = cvt8(*(const f32x4*)xr, *(const f32x4*)(xr + 4));
        }
#pragma unroll
        for (int ht = 0; ht < 4; ++ht)
#pragma unroll
            for (int mt = 0; mt < 2; ++mt)
                acc[ht][mt] = __builtin_amdgcn_mfma_f32_16x16x32_bf16(
                    a[ht], bb[mt], acc[ht][mt], 0, 0, 0);
    }

    int batch = blockIdx.x >> 4;
    int m_in_b = (blockIdx.x & 15) * 64;
#pragma unroll
    for (int ht = 0; ht < 4; ++ht)
#pragma unroll
        for (int mt = 0; mt < 2; ++mt) {
            int mcol = wave_m + mt * 16 + l16;
#pragma unroll
            for (int r = 0; r < 4; ++r) {
                int h = wave_h + ht * 16 + quad * 4 + r;
                ST[(((size_t)batch * 128 + h) << 10) + m_in_b + mcol] =
                    f2bf(acc[ht][mt][r]);
            }
        }
}

// ---------------- k2: out[b][m][n] = relu(sum_k adj[b][m][k]*S[b][k][n] + bias[n]) ----
// 64m x 128n per block, grid 512, 4 waves (32m x 64n each), BK=64, dbuf LDS.
// Pipeline (tile t lives in reg set R[t&1], LDS buf t&1):
//   body kb: issue loads(kb+2)->R[kb&1]; MFMA(LDS[kb&1]);
//            ds_write tile kb+1 from R[(kb+1)&1] (compiler emits COUNTED
//            vmcnt(8): waits kb+1's loads, leaves kb+2's in flight);
//            BAR_LGKM (loads cross the barrier).
#define K2S 72  // LDS row stride (bf16): 144B = 9*16B -> uniform b128 bank slots
__global__ __launch_bounds__(256, 2) void k2_gcn(const float* __restrict__ adj,
                                                 const unsigned short* __restrict__ ST,
                                                 const float* __restrict__ bias,
                                                 float* __restrict__ out) {
    __shared__ __align__(16) unsigned short As[2][64 * K2S];   // adj tile [m][k] bf16
    __shared__ __align__(16) unsigned short Bs[2][128 * K2S];  // ST tile [n][k] bf16
    int t = threadIdx.x;
    int batch = blockIdx.x >> 4;
    int mbase = (blockIdx.x & 15) * 64;
    int wv = t >> 6, lane = t & 63, l16 = lane & 15, quad = lane >> 4;
    int wave_m = (wv & 1) * 32, wave_n = (wv >> 1) * 64;

    float bv[4];
#pragma unroll
    for (int j = 0; j < 4; ++j) bv[j] = bias[wave_n + j * 16 + l16];

    f32x4 acc[2][4];
#pragma unroll
    for (int i = 0; i < 2; ++i)
#pragma unroll
        for (int j = 0; j < 4; ++j) acc[i][j] = 0.f;

    const float* adjb = adj + ((size_t)batch * 1024 + mbase) * 1024;
    const unsigned short* stb = ST + ((size_t)batch * 128) * 1024;

    int ar_row = t >> 4, ar_c4 = t & 15;   // adj staging: rows i*16+ar_row
    int sr_row = t >> 3, sr_ch = t & 7;    // ST staging: rows i*32+sr_row

    f32x4 avA[4], avB[4];   // adj staging regs (f32, cvt on LDS write)
    i32x4 svA[4], svB[4];   // ST staging regs (bf16 payload)

    auto LOAD = [&](int kb, f32x4 (&av)[4], i32x4 (&sv)[4]) {
#pragma unroll
        for (int i = 0; i < 4; ++i)
            av[i] = *(const f32x4*)(adjb + (size_t)(i * 16 + ar_row) * 1024 +
                                    kb * 64 + ar_c4 * 4);
#pragma unroll
        for (int i = 0; i < 4; ++i)
            sv[i] = *(const i32x4*)(stb + (size_t)(i * 32 + sr_row) * 1024 +
                                    kb * 64 + sr_ch * 8);
    };
    auto WRITE = [&](int buf, f32x4 (&av)[4], i32x4 (&sv)[4]) {
#pragma unroll
        for (int i = 0; i < 4; ++i) {
            u16x4 p;
            p.x = f2bf(av[i].x); p.y = f2bf(av[i].y);
            p.z = f2bf(av[i].z); p.w = f2bf(av[i].w);
            *(u16x4*)&As[buf][(i * 16 + ar_row) * K2S + ar_c4 * 4] = p;
        }
#pragma unroll
        for (int i = 0; i < 4; ++i)
            *(i32x4*)&Bs[buf][(i * 32 + sr_row) * K2S + sr_ch * 8] = sv[i];
    };
    auto MFMA = [&](int buf) {
#pragma unroll
        for (int s = 0; s < 2; ++s) {
            int ko = s * 32 + quad * 8;
            bf16x8 a[2], bb[4];
#pragma unroll
            for (int i = 0; i < 2; ++i)
                a[i] = *(const bf16x8*)&As[buf][(wave_m + i * 16 + l16) * K2S + ko];
#pragma unroll
            for (int j = 0; j < 4; ++j)
                bb[j] = *(const bf16x8*)&Bs[buf][(wave_n + j * 16 + l16) * K2S + ko];
#pragma unroll
            for (int i = 0; i < 2; ++i)
#pragma unroll
                for (int j = 0; j < 4; ++j)
                    acc[i][j] = __builtin_amdgcn_mfma_f32_16x16x32_bf16(
                        a[i], bb[j], acc[i][j], 0, 0, 0);
        }
    };

    // prologue: tile0 -> LDS0; tile1 -> regs B; loads for tile2 issue in body.
    LOAD(0, avA, svA);
    WRITE(0, avA, svA);
    LOAD(1, avB, svB);
    BAR_LGKM();

    for (int j = 0; j < 8; ++j) {
        int kb = 2 * j;
        // even body: compute tile kb (buf0), stage tile kb+1 (buf1)
        if (kb + 2 < 16) LOAD(kb + 2, avA, svA);
        MFMA(0);
        WRITE(1, avB, svB);   // counted vmcnt: kb+2 loads stay in flight
        BAR_LGKM();
        // odd body: compute tile kb+1 (buf1), stage tile kb+2 (buf0)
        if (kb + 3 < 16) LOAD(kb + 3, avB, svB);
        MFMA(1);
        if (kb + 1 < 15) {
            WRITE(0, avA, svA);
            BAR_LGKM();
        }
    }

    float* outb = out + ((size_t)batch * 1024 + mbase) * 128;
#pragma unroll
    for (int i = 0; i < 2; ++i)
#pragma unroll
        for (int j = 0; j < 4; ++j) {
            int n = wave_n + j * 16 + l16;
#pragma unroll
            for (int r = 0; r < 4; ++r) {
                int m = wave_m + i * 16 + quad * 4 + r;
                float v = acc[i][j][r] + bv[j];
                outb[(size_t)m * 128 + n] = fmaxf(v, 0.f);
            }
        }
}

extern "C" void kernel_launch(void* const* d_in, const int* in_sizes, int n_in,
                              void* d_out, int out_size, void* d_ws, size_t ws_size,
                              hipStream_t stream) {
    const float* x = (const float*)d_in[0];
    const float* adj = (const float*)d_in[1];
    const float* W = (const float*)d_in[2];
    const float* b = (const float*)d_in[3];
    float* out = (float*)d_out;

    // ws layout: ST bf16 [32][128][1024] = 8 MiB, then WT bf16 [128][128] = 32 KiB
    unsigned short* ST = (unsigned short*)d_ws;
    unsigned short* WT = (unsigned short*)d_ws + (size_t)32 * 128 * 1024;

    k0_wt<<<64, 256, 0, stream>>>(W, WT);
    k1_support<<<512, 256, 0, stream>>>(x, WT, ST);
    k2_gcn<<<512, 256, 0, stream>>>(adj, ST, b, out);
}